// Round 1
// baseline (830.114 us; speedup 1.0000x reference)
//
#include <hip/hip_runtime.h>

// Space-to-depth reorg (stride 2), fp32.
// in : (32, 64, 256, 256)   out: (32, 256, 128, 128)
// out[b, i*4 + l*2 + m, oy, ox] = x[b, i, 2*oy + l, 2*ox + m]
//
// Each thread: reads 8 consecutive floats (2x float4) from one input row,
// writes 2x float4 (even cols -> channel c0, odd cols -> channel c0+1).
// Both global read and write are 16B/lane coalesced.

constexpr int B  = 32;
constexpr int C  = 64;
constexpr int H  = 256;
constexpr int W  = 256;
constexpr int OH = H / 2;   // 128
constexpr int OW = W / 2;   // 128

__global__ __launch_bounds__(256) void reorg_kernel(const float* __restrict__ x,
                                                    float* __restrict__ out) {
    const unsigned t = blockIdx.x * blockDim.x + threadIdx.x;
    // Each thread owns 8 consecutive input floats.
    const unsigned xgrp  = t & 31u;        // which 8-float chunk in the row (W/8 = 32)
    const unsigned row   = t >> 5;         // (b*C + i)*H + y
    const unsigned y     = row & (H - 1);
    const unsigned plane = row >> 8;       // / H
    const unsigned i     = plane & (C - 1);
    const unsigned b     = plane >> 6;     // / C

    const float4* __restrict__ xin =
        reinterpret_cast<const float4*>(x + (size_t)row * W + xgrp * 8u);
    const float4 f0 = xin[0];
    const float4 f1 = xin[1];

    const unsigned oy = y >> 1;
    const unsigned l  = y & 1u;
    const unsigned ox = xgrp * 4u;
    const unsigned c0 = i * 4u + l * 2u;

    float4 ev;  // even input columns -> channel c0
    ev.x = f0.x; ev.y = f0.z; ev.z = f1.x; ev.w = f1.z;
    float4 od;  // odd input columns -> channel c0+1
    od.x = f0.y; od.y = f0.w; od.z = f1.y; od.w = f1.w;

    const size_t obase =
        (((size_t)(b * (C * 4) + c0) * OH) + oy) * OW + ox;
    *reinterpret_cast<float4*>(out + obase) = ev;
    *reinterpret_cast<float4*>(out + obase + (size_t)OH * OW) = od;
}

extern "C" void kernel_launch(void* const* d_in, const int* in_sizes, int n_in,
                              void* d_out, int out_size, void* d_ws, size_t ws_size,
                              hipStream_t stream) {
    const float* x = (const float*)d_in[0];
    float* out = (float*)d_out;

    const unsigned total_threads = (unsigned)(B * C * H * W / 8); // 16,777,216
    const unsigned block = 256;
    const unsigned grid = total_threads / block;                  // 65,536

    reorg_kernel<<<grid, block, 0, stream>>>(x, out);
}